// Round 1
// 5330.985 us; speedup vs baseline: 1.0944x; 1.0944x over previous
//
#include <hip/hip_runtime.h>

// Problem constants (match reference)
#define NB 512   // batch
#define NT 512   // time
#define NI 128   // input dim
#define NH 256   // hidden dim
#define NG 1024  // 4*NH gate rows
#define NKW 384  // NI + NH fused K
#define NKT 12   // K tiles of 32 (MFMA K)
#define NMT 8    // M tiles of 16 per wave (8 waves * 8 * 16 = 1024 rows)
#define NWAVE 8
#define NFRAG 96 // NMT*NKT fragments per wave
// W fragment residency split (per m-tile, by kt):  kt 0..2 -> VGPR,
// kt 3..4 -> LDS, kt 5..11 -> streamed from L2 every step.
#define KT_REG 3
#define KT_LDS 2
#define KT_STR 7
#define EPSV 1e-5f

typedef short short8 __attribute__((ext_vector_type(8)));  // 8 bf16 = one MFMA A/B frag
typedef float f32x4 __attribute__((ext_vector_type(4)));   // MFMA C/D frag

__device__ __forceinline__ unsigned short f32_to_bf16(float f) {
  unsigned int u = __float_as_uint(f);
  u += 0x7fffu + ((u >> 16) & 1u);   // round-to-nearest-even
  return (unsigned short)(u >> 16);
}

// ---------------------------------------------------------------------------
// Prep 1: W in MFMA A-fragment order, bf16.
// Fragment (w, m, kt): lane l holds 8 contiguous-k bf16 of
//   row = w*128 + m*16 + (l&15),  k = kt*32 + (l>>4)*8 + e   (e = 0..7)
// stored at element ((w*96 + m*12 + kt)*64 + l)*8 + e  -> lane j reads 16 B at
// 16*j: fully coalesced dwordx4 loads, zero shuffle into MFMA operands.
// The same (lane-group, e) -> k convention is used for the B operand (xh),
// so the result is invariant to the HW's internal k ordering.
// Also bsum = b_ih + b_hh.
// ---------------------------------------------------------------------------
__global__ void prep_kernel(const float* __restrict__ W_ih, const float* __restrict__ W_hh,
                            const float* __restrict__ b_ih, const float* __restrict__ b_hh,
                            unsigned short* __restrict__ Wf, float* __restrict__ bsum) {
  int o = blockIdx.x * blockDim.x + threadIdx.x;   // over 1024*384 elements
  if (o < NG * NKW) {
    int e = o & 7;
    int l = (o >> 3) & 63;
    int v = o >> 9;              // w*96 + fi
    int fi = v % NFRAG;
    int w = v / NFRAG;
    int m = fi / NKT, kt = fi % NKT;
    int row = w * 128 + m * 16 + (l & 15);
    int k = kt * 32 + ((l >> 4) << 3) + e;
    float val = (k < NI) ? W_ih[row * NI + k] : W_hh[row * NH + (k - NI)];
    Wf[o] = f32_to_bf16(val);
  }
  if (o < NG) bsum[o] = b_ih[o] + b_hh[o];
}

// ---------------------------------------------------------------------------
// Prep 2: rank-sort sequences by length (descending) -> perm.
// ---------------------------------------------------------------------------
__global__ void sort_kernel(const int* __restrict__ lengths, int* __restrict__ perm) {
  int i = threadIdx.x;
  __shared__ int L[NB];
  int li = lengths[i];
  L[i] = li;
  __syncthreads();
  int r = 0;
  for (int k = 0; k < NB; ++k) {
    int lk = L[k];
    r += (lk > li) || (lk == li && k < i);
  }
  perm[r] = i;
}

// ---------------------------------------------------------------------------
// Main: one block (512 threads = 8 waves) per PAIR of sorted sequences.
// Per step: gates(1024x2) = W(1024x384) @ xh(384x2) via mfma_f32_16x16x32_bf16,
// N=16 with cols 0/1 = the two sequences (cols 2..15 mirror them; ignored).
// Wave w owns rows [w*128, w*128+128) = 8 m-tiles; acc over 12 k-tiles.
// 24 of 96 W-frags live in VGPRs, 16 in LDS, 56 streamed from L2 each step.
// Gate preacts exchanged through LDS; threads (s=tid>>8, j=tid&255) do the
// pointwise cell update with c,h in fp32 registers (same freeze semantics).
// ---------------------------------------------------------------------------
__global__ __launch_bounds__(512, 2)
void lstm_ln_kernel(const float* __restrict__ X, const int* __restrict__ lengths,
                    const int* __restrict__ perm,
                    const short8* __restrict__ Wf8, const float* __restrict__ bsum,
                    const float* __restrict__ gamma, const float* __restrict__ beta,
                    float* __restrict__ out) {
  const int p = blockIdx.x;
  const int tid = threadIdx.x;
  const int w = tid >> 6;      // wave 0..7
  const int l = tid & 63;      // lane

  __shared__ short8 ldsW[NWAVE * NMT * KT_LDS * 64];            // 128 KB W frags
  __shared__ __align__(16) unsigned short xh[2][NKW];           // bf16 [x | h] per seq
  __shared__ __align__(16) float gates[2][NG];                  // preactivations
  __shared__ float red[20];

  const int b0 = perm[2 * p];
  const int b1 = perm[2 * p + 1];
  const int len0 = lengths[b0];
  const int len1 = lengths[b1];
  const int lmax = (len0 > len1) ? len0 : len1;

  // ---- load resident W fragments (VGPR) and fill LDS fragments ----
  short8 wreg[NMT][KT_REG];
#pragma unroll
  for (int m = 0; m < NMT; ++m)
#pragma unroll
    for (int kt = 0; kt < KT_REG; ++kt)
      wreg[m][kt] = Wf8[(w * NFRAG + m * NKT + kt) * 64 + l];
#pragma unroll
  for (int m = 0; m < NMT; ++m)
#pragma unroll
    for (int q = 0; q < KT_LDS; ++q)
      ldsW[((w * NMT + m) * KT_LDS + q) * 64 + l] =
          Wf8[(w * NFRAG + m * NKT + KT_REG + q) * 64 + l];

  const short8* __restrict__ wstr = Wf8 + (w * NFRAG) * 64 + l;  // streamed frags base

  // ---- pointwise cell mapping ----
  const int s = tid >> 8;       // 0: seq0, 1: seq1
  const int j = tid & 255;      // hidden unit
  const int mylen = s ? len1 : len0;
  const float bsi = bsum[j], bsf = bsum[NH + j], bsg = bsum[2 * NH + j], bso = bsum[3 * NH + j];
  float c = 0.f, h = 0.f;

  const float* __restrict__ xr0 = X + (size_t)b0 * NT * NI;
  const float* __restrict__ xr1 = X + (size_t)b1 * NT * NI;
  const float* __restrict__ pxr = (tid < NI) ? xr0 : xr1;   // x stager (tid < 256)
  const int kx = tid & 127;

  // init xh: h part = 0, x part = x_0
  xh[s][NI + j] = 0;
  if (tid < 2 * NI) xh[tid >> 7][kx] = f32_to_bf16(pxr[kx]);
  __syncthreads();

  const int bcol = l & 1;     // B col -> seq (cols 2..15 mirror 0/1; ignored in D)
  const int kg = l >> 4;      // k-group within k-tile

  for (int t = 0; t < lmax; ++t) {
    // ---------------- phase A: GEMV via MFMA ----------------
    // prefetch next x into regs early; latency hides under the MFMAs
    float xnext = 0.f;
    if (tid < 2 * NI) {
      int tn = (t + 1 < NT) ? (t + 1) : t;
      xnext = pxr[(size_t)tn * NI + kx];
    }

    short8 bf[NKT];
#pragma unroll
    for (int kt = 0; kt < NKT; ++kt)
      bf[kt] = *(const short8*)&xh[bcol][kt * 32 + kg * 8];

    f32x4 acc[NMT];
#pragma unroll
    for (int m = 0; m < NMT; ++m) acc[m] = (f32x4){0.f, 0.f, 0.f, 0.f};

#pragma unroll
    for (int m = 0; m < NMT; ++m) {
      short8 sw[KT_STR];
#pragma unroll
      for (int q = 0; q < KT_STR; ++q)
        sw[q] = wstr[(m * NKT + KT_REG + KT_LDS + q) * 64];
#pragma unroll
      for (int kt = 0; kt < KT_REG; ++kt)
        acc[m] = __builtin_amdgcn_mfma_f32_16x16x32_bf16(wreg[m][kt], bf[kt], acc[m], 0, 0, 0);
#pragma unroll
      for (int q = 0; q < KT_LDS; ++q)
        acc[m] = __builtin_amdgcn_mfma_f32_16x16x32_bf16(
            ldsW[((w * NMT + m) * KT_LDS + q) * 64 + l], bf[KT_REG + q], acc[m], 0, 0, 0);
#pragma unroll
      for (int q = 0; q < KT_STR; ++q)
        acc[m] = __builtin_amdgcn_mfma_f32_16x16x32_bf16(sw[q], bf[KT_REG + KT_LDS + q],
                                                         acc[m], 0, 0, 0);
    }

    // D layout (m89-verified): lane l, reg r -> row (l>>4)*4 + r, col l&15.
    // Lanes with col < 2 write their 4 contiguous rows per m-tile.
    if ((l & 15) < 2) {
#pragma unroll
      for (int m = 0; m < NMT; ++m)
        *(f32x4*)&gates[l & 1][w * 128 + m * 16 + ((l >> 4) << 2)] = acc[m];
    }
    __syncthreads();

    // ---------------- phase B: pointwise cell update ----------------
    {
      float pi = gates[s][j] + bsi;
      float pf = gates[s][NH + j] + bsf;
      float pg = gates[s][2 * NH + j] + bsg;
      float po = gates[s][3 * NH + j] + bso;
      if (t < mylen) {
        float ig = 1.f / (1.f + __expf(-pi));
        float fg = 1.f / (1.f + __expf(-pf));
        float gv = 1.f - 2.f / (1.f + __expf(2.f * pg));
        float og = 1.f / (1.f + __expf(-po));
        c = fg * c + ig * gv;
        h = og * (1.f - 2.f / (1.f + __expf(2.f * c)));
        xh[s][NI + j] = f32_to_bf16(h);
      }
    }
    if (tid < 2 * NI) xh[tid >> 7][kx] = f32_to_bf16(xnext);
    __syncthreads();
  }

  // ---- LayerNorm over H=256 per sequence (waves 0-3: seq0, 4-7: seq1) ----
  float sum = h, sq = h * h;
#pragma unroll
  for (int off = 32; off > 0; off >>= 1) {
    sum += __shfl_xor(sum, off);
    sq  += __shfl_xor(sq, off);
  }
  if (l == 0) { red[w] = sum; red[8 + w] = sq; }
  __syncthreads();
  if (tid == 0) {
    float S = red[0] + red[1] + red[2] + red[3];
    float Q = red[8] + red[9] + red[10] + red[11];
    float mu = S * (1.f / NH);
    red[16] = mu;
    red[17] = rsqrtf(Q * (1.f / NH) - mu * mu + EPSV);
  }
  if (tid == 256) {
    float S = red[4] + red[5] + red[6] + red[7];
    float Q = red[12] + red[13] + red[14] + red[15];
    float mu = S * (1.f / NH);
    red[18] = mu;
    red[19] = rsqrtf(Q * (1.f / NH) - mu * mu + EPSV);
  }
  __syncthreads();
  {
    float mu = red[16 + 2 * s], rstd = red[17 + 2 * s];
    int b = s ? b1 : b0;
    out[(size_t)b * NH + j] = (h - mu) * rstd * gamma[j] + beta[j];
  }
}

extern "C" void kernel_launch(void* const* d_in, const int* in_sizes, int n_in,
                              void* d_out, int out_size, void* d_ws, size_t ws_size,
                              hipStream_t stream) {
  const float* X       = (const float*)d_in[0];
  const int*   lengths = (const int*)d_in[1];
  const float* W_ih    = (const float*)d_in[2];
  const float* W_hh    = (const float*)d_in[3];
  const float* b_ih    = (const float*)d_in[4];
  const float* b_hh    = (const float*)d_in[5];
  const float* gamma   = (const float*)d_in[6];
  const float* beta    = (const float*)d_in[7];
  float* out = (float*)d_out;

  // workspace layout (same footprint as before: ~774 KB)
  unsigned short* Wf = (unsigned short*)d_ws;                                   // 768 KB
  float* bsum = (float*)((char*)d_ws + (size_t)NG * NKW * sizeof(unsigned short)); // 4 KB
  int* perm = (int*)((char*)bsum + NG * sizeof(float));                            // 2 KB

  int total = NG * NKW;
  prep_kernel<<<(total + 255) / 256, 256, 0, stream>>>(W_ih, W_hh, b_ih, b_hh, Wf, bsum);
  sort_kernel<<<1, NB, 0, stream>>>(lengths, perm);
  lstm_ln_kernel<<<NB / 2, 512, 0, stream>>>(X, lengths, perm, (const short8*)Wf, bsum,
                                             gamma, beta, out);
}

// Round 3
// 2699.255 us; speedup vs baseline: 2.1614x; 1.9750x over previous
//
#include <hip/hip_runtime.h>

// Problem constants (match reference)
#define NB 512   // batch
#define NT 512   // time
#define NI 128   // input dim  (K_x, 4 k-tiles)
#define NH 256   // hidden dim (K_h, 8 k-tiles)
#define NG 1024  // 4*NH gate rows
#define NMT 8    // m-tiles of 16 per wave (8 waves * 8 * 16 = 1024 rows)
#define NWAVE 8
#define CH 8     // chunk = 8 time steps of x-projection per pass
#define EPSV 1e-5f

// W_hh frag f=(w*8+m)*8+kt  at Wf8[f*64+l]          (512 frags, 512 KB)
// W_ih frag g=(w*8+m)*4+kx  at Wf8[32768 + g*64+l]  (256 frags, 256 KB)
#define WXOFF 32768

typedef short short8 __attribute__((ext_vector_type(8)));  // 8 bf16 = MFMA A/B frag
typedef float f32x4 __attribute__((ext_vector_type(4)));   // MFMA C/D frag

__device__ __forceinline__ unsigned short f32_to_bf16(float f) {
  unsigned int u = __float_as_uint(f);
  u += 0x7fffu + ((u >> 16) & 1u);   // round-to-nearest-even
  return (unsigned short)(u >> 16);
}
__device__ __forceinline__ float bf16_to_f32(unsigned short u) {
  return __uint_as_float(((unsigned int)u) << 16);
}

// ---------------------------------------------------------------------------
// Prep 1: W_hh and W_ih in MFMA A-fragment order, bf16.
// Fragment: lane l holds 8 contiguous-k bf16 of row = w*128+m*16+(l&15),
// k = kt*32 + (l>>4)*8 + e.  Same (lane-group,e)->k convention used for the
// B operand, so the MFMA result is invariant to HW internal k ordering.
// ---------------------------------------------------------------------------
__global__ void prep_kernel(const float* __restrict__ W_ih, const float* __restrict__ W_hh,
                            const float* __restrict__ b_ih, const float* __restrict__ b_hh,
                            unsigned short* __restrict__ Wf, float* __restrict__ bsum) {
  int o = blockIdx.x * blockDim.x + threadIdx.x;   // over (512+256)*512 elements
  int e = o & 7;
  int l = (o >> 3) & 63;
  int f = o >> 9;
  if (f < 512) {              // W_hh frags
    int kt = f & 7, m = (f >> 3) & 7, w = f >> 6;
    int row = w * 128 + m * 16 + (l & 15);
    int k = kt * 32 + ((l >> 4) << 3) + e;
    Wf[o] = f32_to_bf16(W_hh[row * NH + k]);
  } else if (f < 768) {       // W_ih frags
    int g = f - 512;
    int kx = g & 3, m = (g >> 2) & 7, w = g >> 5;
    int row = w * 128 + m * 16 + (l & 15);
    int k = kx * 32 + ((l >> 4) << 3) + e;
    Wf[o] = f32_to_bf16(W_ih[row * NI + k]);
  }
  if (o < NG) bsum[o] = b_ih[o] + b_hh[o];
}

// ---------------------------------------------------------------------------
// Prep 2: rank-sort sequences by length (descending) -> perm.
// ---------------------------------------------------------------------------
__global__ void sort_kernel(const int* __restrict__ lengths, int* __restrict__ perm) {
  int i = threadIdx.x;
  __shared__ int L[NB];
  int li = lengths[i];
  L[i] = li;
  __syncthreads();
  int r = 0;
  for (int k = 0; k < NB; ++k) {
    int lk = L[k];
    r += (lk > li) || (lk == li && k < i);
  }
  perm[r] = i;
}

// ---------------------------------------------------------------------------
// Main: one block (512 thr = 8 waves) per PAIR of sorted sequences.
// W_hh residency: kt0-4 VGPR (160 regs), kt5 + kt6(m0-5) LDS (112 KB),
// kt6(m6,7) VGPR, kt7 streamed (64 KB/step, L2-hot).
// Every CH=8 steps: x-proj chunk GEMM (two m-halves to cap VGPR pressure),
// N=16 cols = (step,seq); W_ih streamed once per chunk (256 KB, L2-hot);
// result parked bf16 in LDS gx[16][1024].
// Per step: gh = W_hh @ h (64 MFMA/wave); pointwise by (s=tid>>8, j=tid&255),
// c,h in fp32 registers; packed-sequence freeze semantics preserved.
// ---------------------------------------------------------------------------
__global__ __launch_bounds__(512, 2)
void lstm_ln_kernel(const float* __restrict__ X, const int* __restrict__ lengths,
                    const int* __restrict__ perm,
                    const short8* __restrict__ Wf8, const float* __restrict__ bsum,
                    const float* __restrict__ gamma, const float* __restrict__ beta,
                    float* __restrict__ out) {
  const int p = blockIdx.x;
  const int tid = threadIdx.x;
  const int w = tid >> 6;      // wave 0..7
  const int l = tid & 63;      // lane

  __shared__ short8 ldsW[NWAVE * 14 * 64];                   // 112 KB W_hh frags
  __shared__ __align__(16) unsigned short gx[2 * CH][NG];    // 32 KB x-proj bf16
  __shared__ __align__(16) float gh[2][NG];                  // 8 KB h-proj fp32
  __shared__ __align__(16) unsigned short hbuf[2][NH];       // 1 KB h bf16
  __shared__ float red[20];

  const int b0 = perm[2 * p];
  const int b1 = perm[2 * p + 1];
  const int len0 = lengths[b0];
  const int len1 = lengths[b1];
  const int lmax = (len0 > len1) ? len0 : len1;

  // ---- load resident W_hh fragments ----
  short8 wreg[NMT][5];
#pragma unroll
  for (int m = 0; m < NMT; ++m)
#pragma unroll
    for (int kt = 0; kt < 5; ++kt)
      wreg[m][kt] = Wf8[((w * 8 + m) * 8 + kt) * 64 + l];
  short8 w6a = Wf8[((w * 8 + 6) * 8 + 6) * 64 + l];   // kt6, m=6
  short8 w6b = Wf8[((w * 8 + 7) * 8 + 6) * 64 + l];   // kt6, m=7
#pragma unroll
  for (int m = 0; m < NMT; ++m)
    ldsW[(w * 14 + m) * 64 + l] = Wf8[((w * 8 + m) * 8 + 5) * 64 + l];
#pragma unroll
  for (int m = 0; m < 6; ++m)
    ldsW[(w * 14 + 8 + m) * 64 + l] = Wf8[((w * 8 + m) * 8 + 6) * 64 + l];

  // ---- pointwise cell mapping ----
  const int s = tid >> 8;       // 0: seq0, 1: seq1
  const int j = tid & 255;      // hidden unit
  const int mylen = s ? len1 : len0;
  const float bsi = bsum[j], bsf = bsum[NH + j], bsg = bsum[2 * NH + j], bso = bsum[3 * NH + j];
  float c = 0.f, h = 0.f;

  const float* __restrict__ xr0 = X + (size_t)b0 * NT * NI;
  const float* __restrict__ xr1 = X + (size_t)b1 * NT * NI;
  const int seqb = l & 1;                 // B col -> seq (cols replicate mod 2)
  const int kg = l >> 4;                  // k-group within k-tile
  const int st = (l >> 1) & 7;            // chunk step for this lane's column
  const float* __restrict__ xp = seqb ? xr1 : xr0;

  hbuf[s][j] = 0;
  __syncthreads();

  for (int t = 0; t < lmax; ++t) {
    // -------- chunk: x-projection for steps t..t+7 (two m-halves) --------
    if ((t & 7) == 0) {
      // t + st <= 504 + 7 = 511 always in-bounds (lengths <= NT)
      const float* xb = xp + (size_t)(t + st) * NI + kg * 8;
      const int cc = l & 15;
#pragma unroll
      for (int half = 0; half < 2; ++half) {
        f32x4 ax[4];
#pragma unroll
        for (int m = 0; m < 4; ++m) ax[m] = (f32x4){0.f, 0.f, 0.f, 0.f};
#pragma unroll
        for (int kx = 0; kx < 4; ++kx) {
          float4 xa = *(const float4*)(xb + kx * 32);
          float4 xc = *(const float4*)(xb + kx * 32 + 4);
          short8 bx;
          bx[0] = (short)f32_to_bf16(xa.x); bx[1] = (short)f32_to_bf16(xa.y);
          bx[2] = (short)f32_to_bf16(xa.z); bx[3] = (short)f32_to_bf16(xa.w);
          bx[4] = (short)f32_to_bf16(xc.x); bx[5] = (short)f32_to_bf16(xc.y);
          bx[6] = (short)f32_to_bf16(xc.z); bx[7] = (short)f32_to_bf16(xc.w);
#pragma unroll
          for (int m = 0; m < 4; ++m) {
            short8 wi = Wf8[WXOFF + ((w * 8 + half * 4 + m) * 4 + kx) * 64 + l];
            ax[m] = __builtin_amdgcn_mfma_f32_16x16x32_bf16(wi, bx, ax[m], 0, 0, 0);
          }
        }
#pragma unroll
        for (int m = 0; m < 4; ++m) {
          int r0 = w * 128 + (half * 4 + m) * 16 + kg * 4;
          ushort4 pk;
          pk.x = f32_to_bf16(ax[m][0]); pk.y = f32_to_bf16(ax[m][1]);
          pk.z = f32_to_bf16(ax[m][2]); pk.w = f32_to_bf16(ax[m][3]);
          *(ushort4*)&gx[cc][r0] = pk;
        }
      }
      // gx reads happen only after this iteration's __syncthreads() below
    }

    // ---------------- recurrent GEMV: gh = W_hh @ h ----------------
    f32x4 acc[NMT];
#pragma unroll
    for (int m = 0; m < NMT; ++m) acc[m] = (f32x4){0.f, 0.f, 0.f, 0.f};

#pragma unroll
    for (int kt = 0; kt < 5; ++kt) {
      short8 bh = *(const short8*)&hbuf[seqb][kt * 32 + kg * 8];
#pragma unroll
      for (int m = 0; m < NMT; ++m)
        acc[m] = __builtin_amdgcn_mfma_f32_16x16x32_bf16(wreg[m][kt], bh, acc[m], 0, 0, 0);
    }
    // streamed kt7 loads issued in two halves to cap in-flight VGPRs
    short8 sw[NMT];
#pragma unroll
    for (int m = 0; m < 4; ++m)
      sw[m] = Wf8[((w * 8 + m) * 8 + 7) * 64 + l];
    {
      short8 bh = *(const short8*)&hbuf[seqb][5 * 32 + kg * 8];
#pragma unroll
      for (int m = 0; m < NMT; ++m)
        acc[m] = __builtin_amdgcn_mfma_f32_16x16x32_bf16(ldsW[(w * 14 + m) * 64 + l], bh,
                                                         acc[m], 0, 0, 0);
    }
    short8 bh7 = *(const short8*)&hbuf[seqb][7 * 32 + kg * 8];
#pragma unroll
    for (int m = 0; m < 4; ++m)
      acc[m] = __builtin_amdgcn_mfma_f32_16x16x32_bf16(sw[m], bh7, acc[m], 0, 0, 0);
#pragma unroll
    for (int m = 4; m < 8; ++m)
      sw[m] = Wf8[((w * 8 + m) * 8 + 7) * 64 + l];
    {
      short8 bh = *(const short8*)&hbuf[seqb][6 * 32 + kg * 8];
#pragma unroll
      for (int m = 0; m < 6; ++m)
        acc[m] = __builtin_amdgcn_mfma_f32_16x16x32_bf16(ldsW[(w * 14 + 8 + m) * 64 + l], bh,
                                                         acc[m], 0, 0, 0);
      acc[6] = __builtin_amdgcn_mfma_f32_16x16x32_bf16(w6a, bh, acc[6], 0, 0, 0);
      acc[7] = __builtin_amdgcn_mfma_f32_16x16x32_bf16(w6b, bh, acc[7], 0, 0, 0);
    }
#pragma unroll
    for (int m = 4; m < 8; ++m)
      acc[m] = __builtin_amdgcn_mfma_f32_16x16x32_bf16(sw[m], bh7, acc[m], 0, 0, 0);

    // D layout: lane l, reg r -> row (l>>4)*4 + r, col l&15.  Cols 0/1 = seqs.
    if ((l & 15) < 2) {
#pragma unroll
      for (int m = 0; m < NMT; ++m)
        *(f32x4*)&gh[l & 1][w * 128 + m * 16 + kg * 4] = acc[m];
    }
    __syncthreads();

    // ---------------- pointwise cell update ----------------
    {
      const int dt = ((t & 7) << 1) + s;
      float pi = gh[s][j]          + bf16_to_f32(gx[dt][j])          + bsi;
      float pf = gh[s][NH + j]     + bf16_to_f32(gx[dt][NH + j])     + bsf;
      float pg = gh[s][2 * NH + j] + bf16_to_f32(gx[dt][2 * NH + j]) + bsg;
      float po = gh[s][3 * NH + j] + bf16_to_f32(gx[dt][3 * NH + j]) + bso;
      if (t < mylen) {
        float ig = 1.f / (1.f + __expf(-pi));
        float fg = 1.f / (1.f + __expf(-pf));
        float gv = 1.f - 2.f / (1.f + __expf(2.f * pg));
        float og = 1.f / (1.f + __expf(-po));
        c = fg * c + ig * gv;
        h = og * (1.f - 2.f / (1.f + __expf(2.f * c)));
        hbuf[s][j] = f32_to_bf16(h);
      }
    }
    __syncthreads();
  }

  // ---- LayerNorm over H=256 per sequence (waves 0-3: seq0, 4-7: seq1) ----
  float sum = h, sq = h * h;
#pragma unroll
  for (int off = 32; off > 0; off >>= 1) {
    sum += __shfl_xor(sum, off);
    sq  += __shfl_xor(sq, off);
  }
  if (l == 0) { red[w] = sum; red[8 + w] = sq; }
  __syncthreads();
  if (tid == 0) {
    float S = red[0] + red[1] + red[2] + red[3];
    float Q = red[8] + red[9] + red[10] + red[11];
    float mu = S * (1.f / NH);
    red[16] = mu;
    red[17] = rsqrtf(Q * (1.f / NH) - mu * mu + EPSV);
  }
  if (tid == 256) {
    float S = red[4] + red[5] + red[6] + red[7];
    float Q = red[12] + red[13] + red[14] + red[15];
    float mu = S * (1.f / NH);
    red[18] = mu;
    red[19] = rsqrtf(Q * (1.f / NH) - mu * mu + EPSV);
  }
  __syncthreads();
  {
    float mu = red[16 + 2 * s], rstd = red[17 + 2 * s];
    int b = s ? b1 : b0;
    out[(size_t)b * NH + j] = (h - mu) * rstd * gamma[j] + beta[j];
  }
}

extern "C" void kernel_launch(void* const* d_in, const int* in_sizes, int n_in,
                              void* d_out, int out_size, void* d_ws, size_t ws_size,
                              hipStream_t stream) {
  const float* X       = (const float*)d_in[0];
  const int*   lengths = (const int*)d_in[1];
  const float* W_ih    = (const float*)d_in[2];
  const float* W_hh    = (const float*)d_in[3];
  const float* b_ih    = (const float*)d_in[4];
  const float* b_hh    = (const float*)d_in[5];
  const float* gamma   = (const float*)d_in[6];
  const float* beta    = (const float*)d_in[7];
  float* out = (float*)d_out;

  // workspace layout (768 KB weights + 4 KB bsum + 2 KB perm, same as before)
  unsigned short* Wf = (unsigned short*)d_ws;
  float* bsum = (float*)((char*)d_ws + (size_t)768 * 512 * sizeof(unsigned short));
  int* perm = (int*)((char*)bsum + NG * sizeof(float));

  int total = 768 * 512;   // (512 W_hh + 256 W_ih frags) * 512 elems
  prep_kernel<<<(total + 255) / 256, 256, 0, stream>>>(W_ih, W_hh, b_ih, b_hh, Wf, bsum);
  sort_kernel<<<1, NB, 0, stream>>>(lengths, perm);
  lstm_ln_kernel<<<NB / 2, 512, 0, stream>>>(X, lengths, perm, (const short8*)Wf, bsum,
                                             gamma, beta, out);
}